// Round 5
// baseline (263.696 us; speedup 1.0000x reference)
//
#include <hip/hip_runtime.h>
#include <math.h>
#include <stdint.h>

typedef unsigned short u16;
typedef unsigned long long u64;
typedef __attribute__((ext_vector_type(8))) short bf16x8;   // 8 bf16 (4 VGPRs)
typedef __attribute__((ext_vector_type(4))) float f32x4;

#define RSQRT1_2F 0.70710678118654752440f

// ---------------------------------------------------------------------------
// helpers
// ---------------------------------------------------------------------------
__device__ __forceinline__ u16 rne_bf16(float x) {
  unsigned u = __float_as_uint(x);
  return (u16)((u + 0x7FFFu + ((u >> 16) & 1u)) >> 16);
}
__device__ __forceinline__ float bf16_to_f(u16 h) {
  return __uint_as_float(((unsigned)h) << 16);
}
__device__ __forceinline__ void gload_lds16(const void* g, void* l) {
  __builtin_amdgcn_global_load_lds(
      (__attribute__((address_space(1))) void*)(uintptr_t)g,
      (__attribute__((address_space(3))) void*)(uintptr_t)l, 16, 0, 0);
}
__device__ __forceinline__ float block_reduce_sum_f(float v, float* smem4) {
  #pragma unroll
  for (int off = 32; off > 0; off >>= 1) v += __shfl_down(v, off, 64);
  const int lane = threadIdx.x & 63;
  const int wid  = threadIdx.x >> 6;
  if (lane == 0) smem4[wid] = v;
  __syncthreads();
  float r = smem4[0] + smem4[1] + smem4[2] + smem4[3];
  __syncthreads();
  return r;
}
__device__ __forceinline__ float gelu_exact(float z) {
  return 0.5f * z * (1.0f + erff(z * RSQRT1_2F));
}

// ---------------------------------------------------------------------------
// prep bodies
// ---------------------------------------------------------------------------
template<int H, int NPT>
__device__ __forceinline__ void ln_split_body(
    const float* __restrict__ x, const float* __restrict__ g,
    const float* __restrict__ b, u16* __restrict__ yhi, u16* __restrict__ ylo,
    int row, float* smem4) {
  const float* xr = x + (size_t)row * H;
  const int tid = threadIdx.x;
  float v[NPT];
  #pragma unroll
  for (int q = 0; q < NPT; ++q) v[q] = xr[tid + q * 256];
  float s = 0.f;
  #pragma unroll
  for (int q = 0; q < NPT; ++q) s += v[q];
  s = block_reduce_sum_f(s, smem4);
  const float mu = s * (1.0f / H);
  float s2 = 0.f;
  #pragma unroll
  for (int q = 0; q < NPT; ++q) { float d = v[q] - mu; s2 = fmaf(d, d, s2); }
  s2 = block_reduce_sum_f(s2, smem4);
  const float rstd = rsqrtf(s2 * (1.0f / H) + 1e-5f);
  #pragma unroll
  for (int q = 0; q < NPT; ++q) {
    const int c = tid + q * 256;
    const float y = (v[q] - mu) * rstd * g[c] + b[c];
    const u16 h = rne_bf16(y);
    const u16 lo = rne_bf16(y - bf16_to_f(h));
    yhi[(size_t)row * H + c] = h;
    ylo[(size_t)row * H + c] = lo;
  }
}

// W[K][N] f32 -> Wt_hi/lo [N][K] bf16, one 64x64 tile.
template<int K, int N>
__device__ __forceinline__ void wsplit_body(
    const float* __restrict__ W, u16* __restrict__ Whi, u16* __restrict__ Wlo,
    int ntile, int ktile, float* sm /* 64*65 floats */) {
  const int t = threadIdx.x;
  const int n0 = ntile * 64, k0 = ktile * 64;
  #pragma unroll
  for (int q = 0; q < 16; ++q) {
    const int r = q * 4 + (t >> 6);
    sm[r * 65 + (t & 63)] = W[(size_t)(k0 + r) * N + n0 + (t & 63)];
  }
  __syncthreads();
  #pragma unroll
  for (int q = 0; q < 16; ++q) {
    const int nr = q * 4 + (t >> 6);
    const int kc = t & 63;
    const float v = sm[kc * 65 + nr];
    const u16 h = rne_bf16(v);
    const u16 lo = rne_bf16(v - bf16_to_f(h));
    Whi[(size_t)(n0 + nr) * K + k0 + kc] = h;
    Wlo[(size_t)(n0 + nr) * K + k0 + kc] = lo;
  }
}

// ---------------------------------------------------------------------------
// prep: blocks [0,4096) = LN1 rows; [4096,4224) = W1 tiles; [4224,4256) = W2.
// ---------------------------------------------------------------------------
__global__ __launch_bounds__(256) void prep_kernel(
    const float* __restrict__ pooled, const float* __restrict__ ln1_g,
    const float* __restrict__ ln1_b, const float* __restrict__ W1,
    const float* __restrict__ W2,
    u16* __restrict__ xhi, u16* __restrict__ xlo,
    u16* __restrict__ w1thi, u16* __restrict__ w1tlo,
    u16* __restrict__ w2thi, u16* __restrict__ w2tlo) {
  __shared__ float sm[64 * 65];
  const int bid = blockIdx.x;
  if (bid < 4096) {
    ln_split_body<1024, 4>(pooled, ln1_g, ln1_b, xhi, xlo, bid, sm);
  } else if (bid < 4224) {
    const int idx = bid - 4096;
    wsplit_body<1024, 512>(W1, w1thi, w1tlo, idx & 7, idx >> 3, sm);
  } else {
    const int idx = bid - 4224;
    wsplit_body<512, 256>(W2, w2thi, w2tlo, idx & 3, idx >> 2, sm);
  }
}

// ---------------------------------------------------------------------------
// LayerNorm over gelu(P1a+P1b+b1) (fused GEMM1 epilogue), split bf16 output.
// ---------------------------------------------------------------------------
template<int H, int NPT>
__global__ __launch_bounds__(256) void ln_gelu_split_kernel(
    const float* __restrict__ Pa, const float* __restrict__ Pb,
    const float* __restrict__ bias, const float* __restrict__ g,
    const float* __restrict__ b, u16* __restrict__ yhi, u16* __restrict__ ylo) {
  __shared__ float smem4[4];
  const int row = blockIdx.x;
  const size_t base = (size_t)row * H;
  const int tid = threadIdx.x;
  float v[NPT];
  #pragma unroll
  for (int q = 0; q < NPT; ++q) {
    const int c = tid + q * 256;
    v[q] = gelu_exact(Pa[base + c] + Pb[base + c] + bias[c]);
  }
  float s = 0.f;
  #pragma unroll
  for (int q = 0; q < NPT; ++q) s += v[q];
  s = block_reduce_sum_f(s, smem4);
  const float mu = s * (1.0f / H);
  float s2 = 0.f;
  #pragma unroll
  for (int q = 0; q < NPT; ++q) { float d = v[q] - mu; s2 = fmaf(d, d, s2); }
  s2 = block_reduce_sum_f(s2, smem4);
  const float rstd = rsqrtf(s2 * (1.0f / H) + 1e-5f);
  #pragma unroll
  for (int q = 0; q < NPT; ++q) {
    const int c = tid + q * 256;
    const float y = (v[q] - mu) * rstd * g[c] + b[c];
    const u16 h = rne_bf16(y);
    const u16 lo = rne_bf16(y - bf16_to_f(h));
    yhi[base + c] = h;
    ylo[base + c] = lo;
  }
}

// ---------------------------------------------------------------------------
// bf16x3 split-MFMA GEMM partial (split-K via z), fp32 output.
// A (hi/lo) [M][K] bf16, B (hi/lo) [N][K] bf16.  BM=128 BN=64 BK=64,
// 256 threads (4 waves, 2x2).  LDS 48KB, rows 128B, XOR swizzle
// byte ^= (row&7)<<4 on pre-swizzled global source AND ds_read (involution).
// XCD-chunked bijective block swizzle (nwg % 8 == 0 both instantiations).
// zclr: if non-null, one thread zeroes the loss accumulators (piggyback).
// ---------------------------------------------------------------------------
template<int M, int N, int K, int KCH>
__global__ __launch_bounds__(256, 2) void gemm_bf16x3_partial(
    const u16* __restrict__ Ahi, const u16* __restrict__ Alo,
    const u16* __restrict__ Bhi, const u16* __restrict__ Blo,
    float* __restrict__ P, double* zclr) {
  if (zclr && blockIdx.x == 0 && blockIdx.y == 0 && blockIdx.z == 0 &&
      threadIdx.x == 0) {
    zclr[0] = 0.0;                      // mse sum
    zclr[1] = 0.0;                      // ordering sum
    ((u64*)zclr)[2] = 0ull;             // mask count
    ((unsigned*)zclr)[6] = 0u;          // ticket
  }
  __shared__ __align__(16) char sb[49152];
  const int t = threadIdx.x;
  const int w = t >> 6;
  const int l = t & 63;
  const int lm = l & 15, lk = l >> 4;
  const int wm = w >> 1, wn = w & 1;

  // XCD-aware chunked remap of the flattened block id (T1).
  const int gx = gridDim.x, gy = gridDim.y;
  const int nwg = gx * gy * gridDim.z;
  const int bid = blockIdx.x + gx * (blockIdx.y + gy * blockIdx.z);
  int swz = (bid & 7) * (nwg >> 3) + (bid >> 3);
  const int bx = swz % gx; swz /= gx;
  const int by = swz % gy;
  const int bz = swz / gy;

  const int m0 = by * 128, n0 = bx * 64;
  const int kbase = bz * KCH;
  float* __restrict__ Pz = P + (size_t)bz * M * N;

  f32x4 acc[4][2];
  #pragma unroll
  for (int m = 0; m < 4; ++m)
    #pragma unroll
    for (int n = 0; n < 2; ++n)
      #pragma unroll
      for (int r = 0; r < 4; ++r) acc[m][n][r] = 0.f;

  const int srow = t >> 3;          // 0..31 within a 32-row chunk
  const int sslot = (t & 7) * 16;   // 16B slot within the 128B row

  for (int k0 = kbase; k0 < kbase + KCH; k0 += 64) {
    #pragma unroll
    for (int q = 0; q < 4; ++q) {
      const int row = q * 32 + srow;
      const int cl = sslot ^ ((row & 7) << 4);
      const size_t gb = ((size_t)(m0 + row) * K + k0) * 2 + cl;
      gload_lds16((const char*)Ahi + gb, sb + q * 4096 + w * 1024);
      gload_lds16((const char*)Alo + gb, sb + 16384 + q * 4096 + w * 1024);
    }
    #pragma unroll
    for (int q = 0; q < 2; ++q) {
      const int row = q * 32 + srow;
      const int cl = sslot ^ ((row & 7) << 4);
      const size_t gb = ((size_t)(n0 + row) * K + k0) * 2 + cl;
      gload_lds16((const char*)Bhi + gb, sb + 32768 + q * 4096 + w * 1024);
      gload_lds16((const char*)Blo + gb, sb + 40960 + q * 4096 + w * 1024);
    }
    __syncthreads();   // compiler drains vmcnt before s_barrier

    #pragma unroll
    for (int kk = 0; kk < 2; ++kk) {
      const int cbase = kk * 64 + lk * 16;
      bf16x8 ah[4], al[4];
      #pragma unroll
      for (int m = 0; m < 4; ++m) {
        const int row = wm * 64 + m * 16 + lm;
        const int c = cbase ^ ((row & 7) << 4);
        ah[m] = *(const bf16x8*)(sb + row * 128 + c);
        al[m] = *(const bf16x8*)(sb + 16384 + row * 128 + c);
      }
      bf16x8 bh[2], bl[2];
      #pragma unroll
      for (int n = 0; n < 2; ++n) {
        const int row = wn * 32 + n * 16 + lm;
        const int c = cbase ^ ((row & 7) << 4);
        bh[n] = *(const bf16x8*)(sb + 32768 + row * 128 + c);
        bl[n] = *(const bf16x8*)(sb + 40960 + row * 128 + c);
      }
      #pragma unroll
      for (int m = 0; m < 4; ++m)
        #pragma unroll
        for (int n = 0; n < 2; ++n) {
          acc[m][n] = __builtin_amdgcn_mfma_f32_16x16x32_bf16(ah[m], bh[n], acc[m][n], 0, 0, 0);
          acc[m][n] = __builtin_amdgcn_mfma_f32_16x16x32_bf16(ah[m], bl[n], acc[m][n], 0, 0, 0);
          acc[m][n] = __builtin_amdgcn_mfma_f32_16x16x32_bf16(al[m], bh[n], acc[m][n], 0, 0, 0);
        }
    }
    __syncthreads();
  }

  #pragma unroll
  for (int m = 0; m < 4; ++m)
    #pragma unroll
    for (int n = 0; n < 2; ++n) {
      const int col = n0 + wn * 32 + n * 16 + lm;
      #pragma unroll
      for (int r = 0; r < 4; ++r) {
        const int row = m0 + wm * 64 + m * 16 + lk * 4 + r;
        Pz[(size_t)row * N + col] = acc[m][n][r];
      }
    }
}

// ---------------------------------------------------------------------------
// Head: h2 = gelu(sum_z P2z + b2) on the fly; z = h2 @ Wh + bh; p = sigmoid.
// Emits logits, T=20*p, E=exp(20*p), L=exp(20*label), MSE partial.
// ---------------------------------------------------------------------------
template<int NZ>
__global__ __launch_bounds__(256) void head_kernel(
    const float* __restrict__ P2, const float* __restrict__ b2,
    const float* __restrict__ Wh, const float* __restrict__ bh,
    const float* __restrict__ labels,
    float* __restrict__ logits_out, float* __restrict__ To,
    float* __restrict__ Eo, float* __restrict__ Lo,
    double* __restrict__ mse_acc) {
  const int lane = threadIdx.x & 63;
  const int wv   = threadIdx.x >> 6;
  const int row  = blockIdx.x * 4 + wv;
  const size_t base = (size_t)row * 256;
  constexpr size_t ZSTRIDE = (size_t)4096 * 256;
  float a0 = 0.f, a1 = 0.f, a2 = 0.f, a3 = 0.f;
  #pragma unroll
  for (int q = 0; q < 4; ++q) {
    const int k = lane + q * 64;
    float s = b2[k];
    #pragma unroll
    for (int z = 0; z < NZ; ++z) s += P2[z * ZSTRIDE + base + k];
    const float hv = gelu_exact(s);
    const float4 wv4 = *(const float4*)&Wh[k * 4];
    a0 = fmaf(hv, wv4.x, a0); a1 = fmaf(hv, wv4.y, a1);
    a2 = fmaf(hv, wv4.z, a2); a3 = fmaf(hv, wv4.w, a3);
  }
  #pragma unroll
  for (int off = 32; off > 0; off >>= 1) {
    a0 += __shfl_down(a0, off, 64);
    a1 += __shfl_down(a1, off, 64);
    a2 += __shfl_down(a2, off, 64);
    a3 += __shfl_down(a3, off, 64);
  }
  if (lane == 0) {
    const float z[4] = {a0 + bh[0], a1 + bh[1], a2 + bh[2], a3 + bh[3]};
    float msew = 0.f;
    #pragma unroll
    for (int d = 0; d < 4; ++d) {
      const float p = 1.0f / (1.0f + expf(-z[d]));
      const float lab = labels[row * 4 + d];
      logits_out[row * 4 + d] = p;
      To[row * 4 + d] = 20.0f * p;
      Eo[row * 4 + d] = expf(20.0f * p);
      Lo[row * 4 + d] = expf(20.0f * lab);
      const float df = p - lab;
      msew = fmaf(df, df, msew);
    }
    atomicAdd(mse_acc, (double)msew);
  }
}

// ---------------------------------------------------------------------------
// Pairwise ordering loss, upper-triangle 64x64 tiles (2080 blocks), with
// fused last-block finalize (ticket + device-scope atomic reads).
//   p = Ei/(Ei+Ej);  log p = Ti - log(Ei+Ej)   (T = 20*logit)
//   bce = log(Ei+Ej) - Tj - t*(Ti-Tj)          (1 log + 1 rcp per element)
// accums layout: [0]=mse d, [1]=ord d, [2]=cnt u64, byte24=ticket u32.
// ---------------------------------------------------------------------------
#define GFUN(t) ((t) * 64 - (t) * ((t) - 1) / 2)

__global__ __launch_bounds__(256) void pairwise_kernel(
    const float* __restrict__ To, const float* __restrict__ E,
    const float* __restrict__ L, const float* __restrict__ labels,
    double* __restrict__ accums, float* __restrict__ out) {
  const int idx = blockIdx.x;
  int ti = (int)((129.0f - sqrtf(fmaxf(16641.0f - 8.0f * (float)idx, 0.f))) * 0.5f);
  if (ti < 0) ti = 0; if (ti > 63) ti = 63;
  while (ti > 0 && GFUN(ti) > idx) ti--;
  while (ti < 63 && GFUN(ti + 1) <= idx) ti++;
  const int tj = ti + (idx - GFUN(ti));
  const int i0 = ti * 64, j0 = tj * 64;

  __shared__ float4 sE[64], sT[64], sL[64], sA[64];
  const int t = threadIdx.x;
  if (t < 64)        sE[t]        = *(const float4*)&E[(size_t)(j0 + t) * 4];
  else if (t < 128)  sT[t - 64]   = *(const float4*)&To[(size_t)(j0 + t - 64) * 4];
  else if (t < 192)  sL[t - 128]  = *(const float4*)&L[(size_t)(j0 + t - 128) * 4];
  else               sA[t - 192]  = *(const float4*)&labels[(size_t)(j0 + t - 192) * 4];

  const int lane = t & 63;
  const int wv   = t >> 6;
  const int i    = i0 + lane;
  const float4 e4 = *(const float4*)&E[(size_t)i * 4];
  const float4 t4 = *(const float4*)&To[(size_t)i * 4];
  const float4 l4 = *(const float4*)&L[(size_t)i * 4];
  const float4 a4 = *(const float4*)&labels[(size_t)i * 4];
  const float Ei[4] = {e4.x, e4.y, e4.z, e4.w};
  const float Ti[4] = {t4.x, t4.y, t4.z, t4.w};
  const float Li[4] = {l4.x, l4.y, l4.z, l4.w};
  const float Ai[4] = {a4.x, a4.y, a4.z, a4.w};
  __syncthreads();

  const bool diag = (ti == tj);
  float acc = 0.f;
  int cnt = 0;
  #pragma unroll 4
  for (int jj = 0; jj < 16; ++jj) {
    const int jl = wv * 16 + jj;
    const bool jok = !diag || (jl > lane);
    const float4 ej4 = sE[jl];
    const float4 tj4 = sT[jl];
    const float4 lj4 = sL[jl];
    const float4 aj4 = sA[jl];
    const float Ej[4] = {ej4.x, ej4.y, ej4.z, ej4.w};
    const float Tj[4] = {tj4.x, tj4.y, tj4.z, tj4.w};
    const float Lj[4] = {lj4.x, lj4.y, lj4.z, lj4.w};
    const float Aj[4] = {aj4.x, aj4.y, aj4.z, aj4.w};
    #pragma unroll
    for (int d = 0; d < 4; ++d) {
      const float logse = __logf(Ei[d] + Ej[d]);
      const float tt = Li[d] * __builtin_amdgcn_rcpf(Li[d] + Lj[d]);
      const float bce = (logse - Tj[d]) - tt * (Ti[d] - Tj[d]);
      const bool m = jok && (fabsf(Ai[d] - Aj[d]) > 0.01f);
      acc += m ? bce : 0.f;
      cnt += m ? 1 : 0;
    }
  }

  #pragma unroll
  for (int off = 32; off > 0; off >>= 1) {
    acc += __shfl_down(acc, off, 64);
    cnt += __shfl_down(cnt, off, 64);
  }
  __shared__ float rf[4];
  __shared__ int   ri[4];
  if (lane == 0) { rf[wv] = acc; ri[wv] = cnt; }
  __syncthreads();
  if (t == 0) {
    atomicAdd(&accums[1], (double)(rf[0] + rf[1] + rf[2] + rf[3]));
    atomicAdd((u64*)accums + 2, (u64)(ri[0] + ri[1] + ri[2] + ri[3]));
    __threadfence();
    unsigned* ticket = (unsigned*)((char*)accums + 24);
    const unsigned old = atomicAdd(ticket, 1u);
    if (old == 2079u) {
      // Device-scope RMW reads: coherent across XCDs.
      const double msum = atomicAdd(&accums[0], 0.0);
      const double osum = atomicAdd(&accums[1], 0.0);
      const u64    c    = atomicAdd((u64*)accums + 2, 0ull);
      const double mse = msum / (4096.0 * 4.0);
      const double ord = (c > 0) ? (osum / (double)c) : 0.0;
      out[0] = (float)(0.5 * mse + 0.5 * ord);
    }
  }
}

// ---------------------------------------------------------------------------
extern "C" void kernel_launch(void* const* d_in, const int* in_sizes, int n_in,
                              void* d_out, int out_size, void* d_ws, size_t ws_size,
                              hipStream_t stream) {
  const float* pooled = (const float*)d_in[0];
  const float* labels = (const float*)d_in[1];
  const float* ln1_g  = (const float*)d_in[2];
  const float* ln1_b  = (const float*)d_in[3];
  const float* W1     = (const float*)d_in[4];
  const float* b1     = (const float*)d_in[5];
  const float* ln2_g  = (const float*)d_in[6];
  const float* ln2_b  = (const float*)d_in[7];
  const float* W2     = (const float*)d_in[8];
  const float* b2     = (const float*)d_in[9];
  const float* Wh     = (const float*)d_in[10];
  const float* bh     = (const float*)d_in[11];
  float* out = (float*)d_out;

  // ws layout (bytes), peak 35651584 (34.0 MiB):
  //  phase1: xhi 8M@0 | xlo 8M@8M | w1thi 1M@16777216 | w1tlo 1M@17825792 |
  //          P1 2x8M@18874368..35651584
  //  phase2 (xhi/xlo/w1t dead): h1nhi 4M@0 | h1nlo 4M@4194304 |
  //          w2thi 256K@8388608 | w2tlo 256K@8650752 |
  //          P2 4x4M@8912896..25690112 (overlaps dead P1 head only)
  //  loss scratch in dead-P1 beyond P2 (zeroed by gemm2, after P1's last
  //          reader): E/T/L 64K each @25690112.. | accums @25886720
  char* ws = (char*)d_ws;
  u16*   xhi   = (u16*)(ws + 0);
  u16*   xlo   = (u16*)(ws + 8388608);
  u16*   w1thi = (u16*)(ws + 16777216);
  u16*   w1tlo = (u16*)(ws + 17825792);
  float* P1    = (float*)(ws + 18874368);
  u16*   h1nhi = (u16*)(ws + 0);
  u16*   h1nlo = (u16*)(ws + 4194304);
  u16*   w2thi = (u16*)(ws + 8388608);
  u16*   w2tlo = (u16*)(ws + 8650752);
  float* P2    = (float*)(ws + 8912896);
  float* Eo    = (float*)(ws + 25690112);
  float* To    = (float*)(ws + 25755648);
  float* Lo    = (float*)(ws + 25821184);
  double* accums = (double*)(ws + 25886720);

  prep_kernel<<<4256, 256, 0, stream>>>(pooled, ln1_g, ln1_b, W1, W2,
                                        xhi, xlo, w1thi, w1tlo, w2thi, w2tlo);
  gemm_bf16x3_partial<4096, 512, 1024, 512><<<dim3(8, 32, 2), 256, 0, stream>>>(
      xhi, xlo, w1thi, w1tlo, P1, nullptr);
  ln_gelu_split_kernel<512, 2><<<4096, 256, 0, stream>>>(
      P1, P1 + (size_t)4096 * 512, b1, ln2_g, ln2_b, h1nhi, h1nlo);
  gemm_bf16x3_partial<4096, 256, 512, 128><<<dim3(4, 32, 4), 256, 0, stream>>>(
      h1nhi, h1nlo, w2thi, w2tlo, P2, accums);
  head_kernel<4><<<1024, 256, 0, stream>>>(
      P2, b2, Wh, bh, labels, out + 1, To, Eo, Lo, &accums[0]);
  pairwise_kernel<<<2080, 256, 0, stream>>>(To, Eo, Lo, labels, accums, out);
}

// Round 6
// 201.685 us; speedup vs baseline: 1.3075x; 1.3075x over previous
//
#include <hip/hip_runtime.h>
#include <math.h>
#include <stdint.h>

typedef unsigned short u16;
typedef unsigned long long u64;
typedef __attribute__((ext_vector_type(8))) short bf16x8;   // 8 bf16 (4 VGPRs)
typedef __attribute__((ext_vector_type(4))) float f32x4;

#define RSQRT1_2F 0.70710678118654752440f

// ---------------------------------------------------------------------------
// helpers
// ---------------------------------------------------------------------------
__device__ __forceinline__ u16 rne_bf16(float x) {
  unsigned u = __float_as_uint(x);
  return (u16)((u + 0x7FFFu + ((u >> 16) & 1u)) >> 16);
}
__device__ __forceinline__ float bf16_to_f(u16 h) {
  return __uint_as_float(((unsigned)h) << 16);
}
__device__ __forceinline__ void gload_lds16(const void* g, void* l) {
  __builtin_amdgcn_global_load_lds(
      (__attribute__((address_space(1))) void*)(uintptr_t)g,
      (__attribute__((address_space(3))) void*)(uintptr_t)l, 16, 0, 0);
}
__device__ __forceinline__ float rlane(float v, int sl) {
  return __uint_as_float((unsigned)__builtin_amdgcn_readlane((int)__float_as_uint(v), sl));
}
__device__ __forceinline__ float block_reduce_sum_f(float v, float* smem4) {
  #pragma unroll
  for (int off = 32; off > 0; off >>= 1) v += __shfl_down(v, off, 64);
  const int lane = threadIdx.x & 63;
  const int wid  = threadIdx.x >> 6;
  if (lane == 0) smem4[wid] = v;
  __syncthreads();
  float r = smem4[0] + smem4[1] + smem4[2] + smem4[3];
  __syncthreads();
  return r;
}
__device__ __forceinline__ float gelu_exact(float z) {
  return 0.5f * z * (1.0f + erff(z * RSQRT1_2F));
}

// ---------------------------------------------------------------------------
// prep bodies
// ---------------------------------------------------------------------------
template<int H, int NPT>
__device__ __forceinline__ void ln_split_body(
    const float* __restrict__ x, const float* __restrict__ g,
    const float* __restrict__ b, u16* __restrict__ yhi, u16* __restrict__ ylo,
    int row, float* smem4) {
  const float* xr = x + (size_t)row * H;
  const int tid = threadIdx.x;
  float v[NPT];
  #pragma unroll
  for (int q = 0; q < NPT; ++q) v[q] = xr[tid + q * 256];
  float s = 0.f;
  #pragma unroll
  for (int q = 0; q < NPT; ++q) s += v[q];
  s = block_reduce_sum_f(s, smem4);
  const float mu = s * (1.0f / H);
  float s2 = 0.f;
  #pragma unroll
  for (int q = 0; q < NPT; ++q) { float d = v[q] - mu; s2 = fmaf(d, d, s2); }
  s2 = block_reduce_sum_f(s2, smem4);
  const float rstd = rsqrtf(s2 * (1.0f / H) + 1e-5f);
  #pragma unroll
  for (int q = 0; q < NPT; ++q) {
    const int c = tid + q * 256;
    const float y = (v[q] - mu) * rstd * g[c] + b[c];
    const u16 h = rne_bf16(y);
    const u16 lo = rne_bf16(y - bf16_to_f(h));
    yhi[(size_t)row * H + c] = h;
    ylo[(size_t)row * H + c] = lo;
  }
}

// W[K][N] f32 -> Wt_hi/lo [N][K] bf16, one 64x64 tile.
template<int K, int N>
__device__ __forceinline__ void wsplit_body(
    const float* __restrict__ W, u16* __restrict__ Whi, u16* __restrict__ Wlo,
    int ntile, int ktile, float* sm /* 64*65 floats */) {
  const int t = threadIdx.x;
  const int n0 = ntile * 64, k0 = ktile * 64;
  #pragma unroll
  for (int q = 0; q < 16; ++q) {
    const int r = q * 4 + (t >> 6);
    sm[r * 65 + (t & 63)] = W[(size_t)(k0 + r) * N + n0 + (t & 63)];
  }
  __syncthreads();
  #pragma unroll
  for (int q = 0; q < 16; ++q) {
    const int nr = q * 4 + (t >> 6);
    const int kc = t & 63;
    const float v = sm[kc * 65 + nr];
    const u16 h = rne_bf16(v);
    const u16 lo = rne_bf16(v - bf16_to_f(h));
    Whi[(size_t)(n0 + nr) * K + k0 + kc] = h;
    Wlo[(size_t)(n0 + nr) * K + k0 + kc] = lo;
  }
}

// ---------------------------------------------------------------------------
// prep: blocks [0,4096) = LN1 rows; [4096,4224) = W1 tiles; [4224,4256) = W2.
// ---------------------------------------------------------------------------
__global__ __launch_bounds__(256) void prep_kernel(
    const float* __restrict__ pooled, const float* __restrict__ ln1_g,
    const float* __restrict__ ln1_b, const float* __restrict__ W1,
    const float* __restrict__ W2,
    u16* __restrict__ xhi, u16* __restrict__ xlo,
    u16* __restrict__ w1thi, u16* __restrict__ w1tlo,
    u16* __restrict__ w2thi, u16* __restrict__ w2tlo) {
  __shared__ float sm[64 * 65];
  const int bid = blockIdx.x;
  if (bid < 4096) {
    ln_split_body<1024, 4>(pooled, ln1_g, ln1_b, xhi, xlo, bid, sm);
  } else if (bid < 4224) {
    const int idx = bid - 4096;
    wsplit_body<1024, 512>(W1, w1thi, w1tlo, idx & 7, idx >> 3, sm);
  } else {
    const int idx = bid - 4224;
    wsplit_body<512, 256>(W2, w2thi, w2tlo, idx & 3, idx >> 2, sm);
  }
}

// ---------------------------------------------------------------------------
// LayerNorm over gelu(P1a+P1b+b1) (fused GEMM1 epilogue), split bf16 output.
// ---------------------------------------------------------------------------
template<int H, int NPT>
__global__ __launch_bounds__(256) void ln_gelu_split_kernel(
    const float* __restrict__ Pa, const float* __restrict__ Pb,
    const float* __restrict__ bias, const float* __restrict__ g,
    const float* __restrict__ b, u16* __restrict__ yhi, u16* __restrict__ ylo) {
  __shared__ float smem4[4];
  const int row = blockIdx.x;
  const size_t base = (size_t)row * H;
  const int tid = threadIdx.x;
  float v[NPT];
  #pragma unroll
  for (int q = 0; q < NPT; ++q) {
    const int c = tid + q * 256;
    v[q] = gelu_exact(Pa[base + c] + Pb[base + c] + bias[c]);
  }
  float s = 0.f;
  #pragma unroll
  for (int q = 0; q < NPT; ++q) s += v[q];
  s = block_reduce_sum_f(s, smem4);
  const float mu = s * (1.0f / H);
  float s2 = 0.f;
  #pragma unroll
  for (int q = 0; q < NPT; ++q) { float d = v[q] - mu; s2 = fmaf(d, d, s2); }
  s2 = block_reduce_sum_f(s2, smem4);
  const float rstd = rsqrtf(s2 * (1.0f / H) + 1e-5f);
  #pragma unroll
  for (int q = 0; q < NPT; ++q) {
    const int c = tid + q * 256;
    const float y = (v[q] - mu) * rstd * g[c] + b[c];
    const u16 h = rne_bf16(y);
    const u16 lo = rne_bf16(y - bf16_to_f(h));
    yhi[base + c] = h;
    ylo[base + c] = lo;
  }
}

// ---------------------------------------------------------------------------
// bf16x3 split-MFMA GEMM partial (split-K via z), fp32 output.
// BM=128 BN=64 BK=64, 256 threads (4 waves, 2x2).  LDS 48KB, rows 128B,
// XOR swizzle byte ^= (row&7)<<4 on pre-swizzled source AND ds_read.
// XCD-chunked bijective block swizzle.  zclr: block0 zeroes the 32-slot
// loss accumulators (3 arrays: mse d[32], ord d[32], cnt u64[32]).
// ---------------------------------------------------------------------------
template<int M, int N, int K, int KCH>
__global__ __launch_bounds__(256, 2) void gemm_bf16x3_partial(
    const u16* __restrict__ Ahi, const u16* __restrict__ Alo,
    const u16* __restrict__ Bhi, const u16* __restrict__ Blo,
    float* __restrict__ P, double* zclr) {
  if (zclr && blockIdx.x == 0 && blockIdx.y == 0 && blockIdx.z == 0 &&
      threadIdx.x < 32) {
    zclr[threadIdx.x] = 0.0;                    // mse slots
    zclr[32 + threadIdx.x] = 0.0;               // ordering slots
    ((u64*)(zclr + 64))[threadIdx.x] = 0ull;    // count slots
  }
  __shared__ __align__(16) char sb[49152];
  const int t = threadIdx.x;
  const int w = t >> 6;
  const int l = t & 63;
  const int lm = l & 15, lk = l >> 4;
  const int wm = w >> 1, wn = w & 1;

  // XCD-aware chunked remap of the flattened block id (T1).
  const int gx = gridDim.x, gy = gridDim.y;
  const int nwg = gx * gy * gridDim.z;
  const int bid = blockIdx.x + gx * (blockIdx.y + gy * blockIdx.z);
  int swz = (bid & 7) * (nwg >> 3) + (bid >> 3);
  const int bx = swz % gx; swz /= gx;
  const int by = swz % gy;
  const int bz = swz / gy;

  const int m0 = by * 128, n0 = bx * 64;
  const int kbase = bz * KCH;
  float* __restrict__ Pz = P + (size_t)bz * M * N;

  f32x4 acc[4][2];
  #pragma unroll
  for (int m = 0; m < 4; ++m)
    #pragma unroll
    for (int n = 0; n < 2; ++n)
      #pragma unroll
      for (int r = 0; r < 4; ++r) acc[m][n][r] = 0.f;

  const int srow = t >> 3;          // 0..31 within a 32-row chunk
  const int sslot = (t & 7) * 16;   // 16B slot within the 128B row

  for (int k0 = kbase; k0 < kbase + KCH; k0 += 64) {
    #pragma unroll
    for (int q = 0; q < 4; ++q) {
      const int row = q * 32 + srow;
      const int cl = sslot ^ ((row & 7) << 4);
      const size_t gb = ((size_t)(m0 + row) * K + k0) * 2 + cl;
      gload_lds16((const char*)Ahi + gb, sb + q * 4096 + w * 1024);
      gload_lds16((const char*)Alo + gb, sb + 16384 + q * 4096 + w * 1024);
    }
    #pragma unroll
    for (int q = 0; q < 2; ++q) {
      const int row = q * 32 + srow;
      const int cl = sslot ^ ((row & 7) << 4);
      const size_t gb = ((size_t)(n0 + row) * K + k0) * 2 + cl;
      gload_lds16((const char*)Bhi + gb, sb + 32768 + q * 4096 + w * 1024);
      gload_lds16((const char*)Blo + gb, sb + 40960 + q * 4096 + w * 1024);
    }
    __syncthreads();   // compiler drains vmcnt before s_barrier

    #pragma unroll
    for (int kk = 0; kk < 2; ++kk) {
      const int cbase = kk * 64 + lk * 16;
      bf16x8 ah[4], al[4];
      #pragma unroll
      for (int m = 0; m < 4; ++m) {
        const int row = wm * 64 + m * 16 + lm;
        const int c = cbase ^ ((row & 7) << 4);
        ah[m] = *(const bf16x8*)(sb + row * 128 + c);
        al[m] = *(const bf16x8*)(sb + 16384 + row * 128 + c);
      }
      bf16x8 bh[2], bl[2];
      #pragma unroll
      for (int n = 0; n < 2; ++n) {
        const int row = wn * 32 + n * 16 + lm;
        const int c = cbase ^ ((row & 7) << 4);
        bh[n] = *(const bf16x8*)(sb + 32768 + row * 128 + c);
        bl[n] = *(const bf16x8*)(sb + 40960 + row * 128 + c);
      }
      #pragma unroll
      for (int m = 0; m < 4; ++m)
        #pragma unroll
        for (int n = 0; n < 2; ++n) {
          acc[m][n] = __builtin_amdgcn_mfma_f32_16x16x32_bf16(ah[m], bh[n], acc[m][n], 0, 0, 0);
          acc[m][n] = __builtin_amdgcn_mfma_f32_16x16x32_bf16(ah[m], bl[n], acc[m][n], 0, 0, 0);
          acc[m][n] = __builtin_amdgcn_mfma_f32_16x16x32_bf16(al[m], bh[n], acc[m][n], 0, 0, 0);
        }
    }
    __syncthreads();
  }

  #pragma unroll
  for (int m = 0; m < 4; ++m)
    #pragma unroll
    for (int n = 0; n < 2; ++n) {
      const int col = n0 + wn * 32 + n * 16 + lm;
      #pragma unroll
      for (int r = 0; r < 4; ++r) {
        const int row = m0 + wm * 64 + m * 16 + lk * 4 + r;
        Pz[(size_t)row * N + col] = acc[m][n][r];
      }
    }
}

// ---------------------------------------------------------------------------
// Head: h2 = gelu(sum_z P2z + b2) on the fly; z = h2 @ Wh + bh; p = sigmoid.
// Emits logits, T=20*p, E=exp(20*p), L=exp(20*label), MSE into spread slots.
// ---------------------------------------------------------------------------
template<int NZ>
__global__ __launch_bounds__(256) void head_kernel(
    const float* __restrict__ P2, const float* __restrict__ b2,
    const float* __restrict__ Wh, const float* __restrict__ bh,
    const float* __restrict__ labels,
    float* __restrict__ logits_out, float* __restrict__ To,
    float* __restrict__ Eo, float* __restrict__ Lo,
    double* __restrict__ mse_slots) {
  const int lane = threadIdx.x & 63;
  const int wv   = threadIdx.x >> 6;
  const int row  = blockIdx.x * 4 + wv;
  const size_t base = (size_t)row * 256;
  constexpr size_t ZSTRIDE = (size_t)4096 * 256;
  float a0 = 0.f, a1 = 0.f, a2 = 0.f, a3 = 0.f;
  #pragma unroll
  for (int q = 0; q < 4; ++q) {
    const int k = lane + q * 64;
    float s = b2[k];
    #pragma unroll
    for (int z = 0; z < NZ; ++z) s += P2[z * ZSTRIDE + base + k];
    const float hv = gelu_exact(s);
    const float4 wv4 = *(const float4*)&Wh[k * 4];
    a0 = fmaf(hv, wv4.x, a0); a1 = fmaf(hv, wv4.y, a1);
    a2 = fmaf(hv, wv4.z, a2); a3 = fmaf(hv, wv4.w, a3);
  }
  #pragma unroll
  for (int off = 32; off > 0; off >>= 1) {
    a0 += __shfl_down(a0, off, 64);
    a1 += __shfl_down(a1, off, 64);
    a2 += __shfl_down(a2, off, 64);
    a3 += __shfl_down(a3, off, 64);
  }
  if (lane == 0) {
    const float z[4] = {a0 + bh[0], a1 + bh[1], a2 + bh[2], a3 + bh[3]};
    float msew = 0.f;
    #pragma unroll
    for (int d = 0; d < 4; ++d) {
      const float p = 1.0f / (1.0f + expf(-z[d]));
      const float lab = labels[row * 4 + d];
      logits_out[row * 4 + d] = p;
      To[row * 4 + d] = 20.0f * p;
      Eo[row * 4 + d] = expf(20.0f * p);
      Lo[row * 4 + d] = expf(20.0f * lab);
      const float df = p - lab;
      msew = fmaf(df, df, msew);
    }
    atomicAdd(&mse_slots[row & 31], (double)msew);
  }
}

// ---------------------------------------------------------------------------
// Pairwise ordering loss: one WAVE per 64x64 upper-triangle tile (2080 tiles,
// 520 blocks x 4 waves).  i-side AND j-side data in registers; j broadcast
// via readlane (uniform index -> SGPR broadcast).  No LDS, no barriers.
//   p = Ei/(Ei+Ej);  log p = Ti - log(Ei+Ej)   (T = 20*logit)
//   bce = log(Ei+Ej) - Tj - t*(Ti-Tj)          (1 log + 1 rcp per element)
// Slot-spread fire-and-forget atomics (32 slots per quantity).
// ---------------------------------------------------------------------------
#define GFUN(t) ((t) * 64 - (t) * ((t) - 1) / 2)

__global__ __launch_bounds__(256) void pairwise_kernel(
    const float* __restrict__ To, const float* __restrict__ E,
    const float* __restrict__ L, const float* __restrict__ labels,
    double* __restrict__ slots) {
  const int lane = threadIdx.x & 63;
  const int wv   = threadIdx.x >> 6;
  const int idx  = blockIdx.x * 4 + wv;

  int ti = (int)((129.0f - sqrtf(fmaxf(16641.0f - 8.0f * (float)idx, 0.f))) * 0.5f);
  if (ti < 0) ti = 0; if (ti > 63) ti = 63;
  while (ti > 0 && GFUN(ti) > idx) ti--;
  while (ti < 63 && GFUN(ti + 1) <= idx) ti++;
  const int tj = ti + (idx - GFUN(ti));
  const int i0 = ti * 64, j0 = tj * 64;
  const int i = i0 + lane, j = j0 + lane;

  const float4 e4 = *(const float4*)&E[(size_t)i * 4];
  const float4 t4 = *(const float4*)&To[(size_t)i * 4];
  const float4 l4 = *(const float4*)&L[(size_t)i * 4];
  const float4 a4 = *(const float4*)&labels[(size_t)i * 4];
  const float Ei[4] = {e4.x, e4.y, e4.z, e4.w};
  const float Ti[4] = {t4.x, t4.y, t4.z, t4.w};
  const float Li[4] = {l4.x, l4.y, l4.z, l4.w};
  const float Ai[4] = {a4.x, a4.y, a4.z, a4.w};
  const float4 ej4 = *(const float4*)&E[(size_t)j * 4];
  const float4 tj4 = *(const float4*)&To[(size_t)j * 4];
  const float4 lj4 = *(const float4*)&L[(size_t)j * 4];
  const float4 aj4 = *(const float4*)&labels[(size_t)j * 4];
  const float Ejv[4] = {ej4.x, ej4.y, ej4.z, ej4.w};
  const float Tjv[4] = {tj4.x, tj4.y, tj4.z, tj4.w};
  const float Ljv[4] = {lj4.x, lj4.y, lj4.z, lj4.w};
  const float Ajv[4] = {aj4.x, aj4.y, aj4.z, aj4.w};

  const bool diag = (ti == tj);
  float acc[4] = {0.f, 0.f, 0.f, 0.f};
  int cnt = 0;
  #pragma unroll 8
  for (int jj = 0; jj < 64; ++jj) {
    const bool jok = !diag || (jj > lane);
    #pragma unroll
    for (int d = 0; d < 4; ++d) {
      const float Ej = rlane(Ejv[d], jj);
      const float Tj = rlane(Tjv[d], jj);
      const float Lj = rlane(Ljv[d], jj);
      const float Aj = rlane(Ajv[d], jj);
      const float logse = __logf(Ei[d] + Ej);
      const float tt = Li[d] * __builtin_amdgcn_rcpf(Li[d] + Lj);
      const float bce = (logse - Tj) - tt * (Ti[d] - Tj);
      const bool m = jok && (fabsf(Ai[d] - Aj) > 0.01f);
      acc[d] += m ? bce : 0.f;
      cnt += m ? 1 : 0;
    }
  }

  float tot = (acc[0] + acc[1]) + (acc[2] + acc[3]);
  #pragma unroll
  for (int off = 32; off > 0; off >>= 1) {
    tot += __shfl_down(tot, off, 64);
    cnt += __shfl_down(cnt, off, 64);
  }
  if (lane == 0) {
    const int sl = idx & 31;
    atomicAdd(&slots[32 + sl], (double)tot);
    atomicAdd((u64*)(slots + 64) + sl, (u64)cnt);
  }
}

// ---------------------------------------------------------------------------
// finalize: reduce the 32-slot accumulators, write the scalar loss.
// ---------------------------------------------------------------------------
__global__ void finalize_kernel(const double* __restrict__ slots,
                                float* __restrict__ out) {
  const int l = threadIdx.x;   // 64 threads
  double m = (l < 32) ? slots[l] : 0.0;
  double o = (l < 32) ? slots[32 + l] : 0.0;
  double c = (l < 32) ? (double)((const u64*)(slots + 64))[l] : 0.0;
  #pragma unroll
  for (int off = 32; off > 0; off >>= 1) {
    m += __shfl_down(m, off, 64);
    o += __shfl_down(o, off, 64);
    c += __shfl_down(c, off, 64);
  }
  if (l == 0) {
    const double mse = m / (4096.0 * 4.0);
    const double ord = (c > 0.0) ? (o / c) : 0.0;
    out[0] = (float)(0.5 * mse + 0.5 * ord);
  }
}

// ---------------------------------------------------------------------------
extern "C" void kernel_launch(void* const* d_in, const int* in_sizes, int n_in,
                              void* d_out, int out_size, void* d_ws, size_t ws_size,
                              hipStream_t stream) {
  const float* pooled = (const float*)d_in[0];
  const float* labels = (const float*)d_in[1];
  const float* ln1_g  = (const float*)d_in[2];
  const float* ln1_b  = (const float*)d_in[3];
  const float* W1     = (const float*)d_in[4];
  const float* b1     = (const float*)d_in[5];
  const float* ln2_g  = (const float*)d_in[6];
  const float* ln2_b  = (const float*)d_in[7];
  const float* W2     = (const float*)d_in[8];
  const float* b2     = (const float*)d_in[9];
  const float* Wh     = (const float*)d_in[10];
  const float* bh     = (const float*)d_in[11];
  float* out = (float*)d_out;

  // ws layout (bytes), peak 35651584 (34.0 MiB):
  //  phase1: xhi 8M@0 | xlo 8M@8M | w1thi 1M@16777216 | w1tlo 1M@17825792 |
  //          P1 2x8M@18874368..35651584
  //  phase2 (xhi/xlo/w1t dead): h1nhi 4M@0 | h1nlo 4M@4194304 |
  //          w2thi 256K@8388608 | w2tlo 256K@8650752 |
  //          P2 4x4M@8912896..25690112 (overlaps dead P1 head only)
  //  loss scratch in dead-P1 beyond P2 (zeroed by gemm2, after P1's last
  //          reader): E/T/L 64K each @25690112.. | slots @25886720
  //          (slots: mse d[32] | ord d[32] | cnt u64[32] = 768 B)
  char* ws = (char*)d_ws;
  u16*   xhi   = (u16*)(ws + 0);
  u16*   xlo   = (u16*)(ws + 8388608);
  u16*   w1thi = (u16*)(ws + 16777216);
  u16*   w1tlo = (u16*)(ws + 17825792);
  float* P1    = (float*)(ws + 18874368);
  u16*   h1nhi = (u16*)(ws + 0);
  u16*   h1nlo = (u16*)(ws + 4194304);
  u16*   w2thi = (u16*)(ws + 8388608);
  u16*   w2tlo = (u16*)(ws + 8650752);
  float* P2    = (float*)(ws + 8912896);
  float* Eo    = (float*)(ws + 25690112);
  float* To    = (float*)(ws + 25755648);
  float* Lo    = (float*)(ws + 25821184);
  double* slots = (double*)(ws + 25886720);

  prep_kernel<<<4256, 256, 0, stream>>>(pooled, ln1_g, ln1_b, W1, W2,
                                        xhi, xlo, w1thi, w1tlo, w2thi, w2tlo);
  gemm_bf16x3_partial<4096, 512, 1024, 512><<<dim3(8, 32, 2), 256, 0, stream>>>(
      xhi, xlo, w1thi, w1tlo, P1, nullptr);
  ln_gelu_split_kernel<512, 2><<<4096, 256, 0, stream>>>(
      P1, P1 + (size_t)4096 * 512, b1, ln2_g, ln2_b, h1nhi, h1nlo);
  gemm_bf16x3_partial<4096, 256, 512, 128><<<dim3(4, 32, 4), 256, 0, stream>>>(
      h1nhi, h1nlo, w2thi, w2tlo, P2, slots);
  head_kernel<4><<<1024, 256, 0, stream>>>(
      P2, b2, Wh, bh, labels, out + 1, To, Eo, Lo, slots);
  pairwise_kernel<<<520, 256, 0, stream>>>(To, Eo, Lo, labels, slots);
  finalize_kernel<<<1, 64, 0, stream>>>(slots, out);
}

// Round 7
// 190.327 us; speedup vs baseline: 1.3855x; 1.0597x over previous
//
#include <hip/hip_runtime.h>
#include <math.h>
#include <stdint.h>

typedef unsigned short u16;
typedef unsigned long long u64;
typedef __attribute__((ext_vector_type(8))) short bf16x8;   // 8 bf16 (4 VGPRs)
typedef __attribute__((ext_vector_type(4))) float f32x4;

#define RSQRT1_2F 0.70710678118654752440f

// ---------------------------------------------------------------------------
// helpers
// ---------------------------------------------------------------------------
__device__ __forceinline__ u16 rne_bf16(float x) {
  unsigned u = __float_as_uint(x);
  return (u16)((u + 0x7FFFu + ((u >> 16) & 1u)) >> 16);
}
__device__ __forceinline__ float bf16_to_f(u16 h) {
  return __uint_as_float(((unsigned)h) << 16);
}
__device__ __forceinline__ void gload_lds16(const void* g, void* l) {
  __builtin_amdgcn_global_load_lds(
      (__attribute__((address_space(1))) void*)(uintptr_t)g,
      (__attribute__((address_space(3))) void*)(uintptr_t)l, 16, 0, 0);
}
__device__ __forceinline__ float rlane(float v, int sl) {
  return __uint_as_float((unsigned)__builtin_amdgcn_readlane((int)__float_as_uint(v), sl));
}
__device__ __forceinline__ float block_reduce_sum_f(float v, float* smem4) {
  #pragma unroll
  for (int off = 32; off > 0; off >>= 1) v += __shfl_down(v, off, 64);
  const int lane = threadIdx.x & 63;
  const int wid  = threadIdx.x >> 6;
  if (lane == 0) smem4[wid] = v;
  __syncthreads();
  float r = smem4[0] + smem4[1] + smem4[2] + smem4[3];
  __syncthreads();
  return r;
}
__device__ __forceinline__ float gelu_exact(float z) {
  return 0.5f * z * (1.0f + erff(z * RSQRT1_2F));
}

// ---------------------------------------------------------------------------
// prep bodies
// ---------------------------------------------------------------------------
template<int H, int NPT>
__device__ __forceinline__ void ln_split_body(
    const float* __restrict__ x, const float* __restrict__ g,
    const float* __restrict__ b, u16* __restrict__ yhi, u16* __restrict__ ylo,
    int row, float* smem4) {
  const float* xr = x + (size_t)row * H;
  const int tid = threadIdx.x;
  float v[NPT];
  #pragma unroll
  for (int q = 0; q < NPT; ++q) v[q] = xr[tid + q * 256];
  float s = 0.f;
  #pragma unroll
  for (int q = 0; q < NPT; ++q) s += v[q];
  s = block_reduce_sum_f(s, smem4);
  const float mu = s * (1.0f / H);
  float s2 = 0.f;
  #pragma unroll
  for (int q = 0; q < NPT; ++q) { float d = v[q] - mu; s2 = fmaf(d, d, s2); }
  s2 = block_reduce_sum_f(s2, smem4);
  const float rstd = rsqrtf(s2 * (1.0f / H) + 1e-5f);
  #pragma unroll
  for (int q = 0; q < NPT; ++q) {
    const int c = tid + q * 256;
    const float y = (v[q] - mu) * rstd * g[c] + b[c];
    const u16 h = rne_bf16(y);
    const u16 lo = rne_bf16(y - bf16_to_f(h));
    yhi[(size_t)row * H + c] = h;
    ylo[(size_t)row * H + c] = lo;
  }
}

// W[K][N] f32 -> Wt_hi/lo [N][K] bf16, one 64x64 tile.
template<int K, int N>
__device__ __forceinline__ void wsplit_body(
    const float* __restrict__ W, u16* __restrict__ Whi, u16* __restrict__ Wlo,
    int ntile, int ktile, float* sm /* 64*65 floats */) {
  const int t = threadIdx.x;
  const int n0 = ntile * 64, k0 = ktile * 64;
  #pragma unroll
  for (int q = 0; q < 16; ++q) {
    const int r = q * 4 + (t >> 6);
    sm[r * 65 + (t & 63)] = W[(size_t)(k0 + r) * N + n0 + (t & 63)];
  }
  __syncthreads();
  #pragma unroll
  for (int q = 0; q < 16; ++q) {
    const int nr = q * 4 + (t >> 6);
    const int kc = t & 63;
    const float v = sm[kc * 65 + nr];
    const u16 h = rne_bf16(v);
    const u16 lo = rne_bf16(v - bf16_to_f(h));
    Whi[(size_t)(n0 + nr) * K + k0 + kc] = h;
    Wlo[(size_t)(n0 + nr) * K + k0 + kc] = lo;
  }
}

// ---------------------------------------------------------------------------
// prep: blocks [0,4096) = LN1 rows; [4096,4224) = W1 tiles; [4224,4256) = W2.
// ---------------------------------------------------------------------------
__global__ __launch_bounds__(256) void prep_kernel(
    const float* __restrict__ pooled, const float* __restrict__ ln1_g,
    const float* __restrict__ ln1_b, const float* __restrict__ W1,
    const float* __restrict__ W2,
    u16* __restrict__ xhi, u16* __restrict__ xlo,
    u16* __restrict__ w1thi, u16* __restrict__ w1tlo,
    u16* __restrict__ w2thi, u16* __restrict__ w2tlo) {
  __shared__ float sm[64 * 65];
  const int bid = blockIdx.x;
  if (bid < 4096) {
    ln_split_body<1024, 4>(pooled, ln1_g, ln1_b, xhi, xlo, bid, sm);
  } else if (bid < 4224) {
    const int idx = bid - 4096;
    wsplit_body<1024, 512>(W1, w1thi, w1tlo, idx & 7, idx >> 3, sm);
  } else {
    const int idx = bid - 4224;
    wsplit_body<512, 256>(W2, w2thi, w2tlo, idx & 3, idx >> 2, sm);
  }
}

// ---------------------------------------------------------------------------
// LayerNorm over gelu(P1a+P1b+b1) (fused GEMM1 epilogue), split bf16 output.
// ---------------------------------------------------------------------------
template<int H, int NPT>
__global__ __launch_bounds__(256) void ln_gelu_split_kernel(
    const float* __restrict__ Pa, const float* __restrict__ Pb,
    const float* __restrict__ bias, const float* __restrict__ g,
    const float* __restrict__ b, u16* __restrict__ yhi, u16* __restrict__ ylo) {
  __shared__ float smem4[4];
  const int row = blockIdx.x;
  const size_t base = (size_t)row * H;
  const int tid = threadIdx.x;
  float v[NPT];
  #pragma unroll
  for (int q = 0; q < NPT; ++q) {
    const int c = tid + q * 256;
    v[q] = gelu_exact(Pa[base + c] + Pb[base + c] + bias[c]);
  }
  float s = 0.f;
  #pragma unroll
  for (int q = 0; q < NPT; ++q) s += v[q];
  s = block_reduce_sum_f(s, smem4);
  const float mu = s * (1.0f / H);
  float s2 = 0.f;
  #pragma unroll
  for (int q = 0; q < NPT; ++q) { float d = v[q] - mu; s2 = fmaf(d, d, s2); }
  s2 = block_reduce_sum_f(s2, smem4);
  const float rstd = rsqrtf(s2 * (1.0f / H) + 1e-5f);
  #pragma unroll
  for (int q = 0; q < NPT; ++q) {
    const int c = tid + q * 256;
    const float y = (v[q] - mu) * rstd * g[c] + b[c];
    const u16 h = rne_bf16(y);
    const u16 lo = rne_bf16(y - bf16_to_f(h));
    yhi[base + c] = h;
    ylo[base + c] = lo;
  }
}

// ---------------------------------------------------------------------------
// bf16x3 split-MFMA GEMM partial (split-K via z), fp32 output.
// BM=128 BN=64 BK=64, 256 threads (4 waves, 2x2).  LDS 48KB, rows 128B,
// XOR swizzle byte ^= (row&7)<<4 on pre-swizzled source AND ds_read.
// XCD-chunked bijective block swizzle.  zclr: block0 zeroes the 32-slot
// loss accumulators (3 arrays: mse d[32], ord d[32], cnt u64[32]).
// ---------------------------------------------------------------------------
template<int M, int N, int K, int KCH>
__global__ __launch_bounds__(256, 2) void gemm_bf16x3_partial(
    const u16* __restrict__ Ahi, const u16* __restrict__ Alo,
    const u16* __restrict__ Bhi, const u16* __restrict__ Blo,
    float* __restrict__ P, double* zclr) {
  if (zclr && blockIdx.x == 0 && blockIdx.y == 0 && blockIdx.z == 0 &&
      threadIdx.x < 32) {
    zclr[threadIdx.x] = 0.0;                    // mse slots
    zclr[32 + threadIdx.x] = 0.0;               // ordering slots
    ((u64*)(zclr + 64))[threadIdx.x] = 0ull;    // count slots
  }
  __shared__ __align__(16) char sb[49152];
  const int t = threadIdx.x;
  const int w = t >> 6;
  const int l = t & 63;
  const int lm = l & 15, lk = l >> 4;
  const int wm = w >> 1, wn = w & 1;

  // XCD-aware chunked remap of the flattened block id (T1).
  const int gx = gridDim.x, gy = gridDim.y;
  const int nwg = gx * gy * gridDim.z;
  const int bid = blockIdx.x + gx * (blockIdx.y + gy * blockIdx.z);
  int swz = (bid & 7) * (nwg >> 3) + (bid >> 3);
  const int bx = swz % gx; swz /= gx;
  const int by = swz % gy;
  const int bz = swz / gy;

  const int m0 = by * 128, n0 = bx * 64;
  const int kbase = bz * KCH;
  float* __restrict__ Pz = P + (size_t)bz * M * N;

  f32x4 acc[4][2];
  #pragma unroll
  for (int m = 0; m < 4; ++m)
    #pragma unroll
    for (int n = 0; n < 2; ++n)
      #pragma unroll
      for (int r = 0; r < 4; ++r) acc[m][n][r] = 0.f;

  const int srow = t >> 3;          // 0..31 within a 32-row chunk
  const int sslot = (t & 7) * 16;   // 16B slot within the 128B row

  for (int k0 = kbase; k0 < kbase + KCH; k0 += 64) {
    #pragma unroll
    for (int q = 0; q < 4; ++q) {
      const int row = q * 32 + srow;
      const int cl = sslot ^ ((row & 7) << 4);
      const size_t gb = ((size_t)(m0 + row) * K + k0) * 2 + cl;
      gload_lds16((const char*)Ahi + gb, sb + q * 4096 + w * 1024);
      gload_lds16((const char*)Alo + gb, sb + 16384 + q * 4096 + w * 1024);
    }
    #pragma unroll
    for (int q = 0; q < 2; ++q) {
      const int row = q * 32 + srow;
      const int cl = sslot ^ ((row & 7) << 4);
      const size_t gb = ((size_t)(n0 + row) * K + k0) * 2 + cl;
      gload_lds16((const char*)Bhi + gb, sb + 32768 + q * 4096 + w * 1024);
      gload_lds16((const char*)Blo + gb, sb + 40960 + q * 4096 + w * 1024);
    }
    __syncthreads();   // compiler drains vmcnt before s_barrier

    #pragma unroll
    for (int kk = 0; kk < 2; ++kk) {
      const int cbase = kk * 64 + lk * 16;
      bf16x8 ah[4], al[4];
      #pragma unroll
      for (int m = 0; m < 4; ++m) {
        const int row = wm * 64 + m * 16 + lm;
        const int c = cbase ^ ((row & 7) << 4);
        ah[m] = *(const bf16x8*)(sb + row * 128 + c);
        al[m] = *(const bf16x8*)(sb + 16384 + row * 128 + c);
      }
      bf16x8 bh[2], bl[2];
      #pragma unroll
      for (int n = 0; n < 2; ++n) {
        const int row = wn * 32 + n * 16 + lm;
        const int c = cbase ^ ((row & 7) << 4);
        bh[n] = *(const bf16x8*)(sb + 32768 + row * 128 + c);
        bl[n] = *(const bf16x8*)(sb + 40960 + row * 128 + c);
      }
      #pragma unroll
      for (int m = 0; m < 4; ++m)
        #pragma unroll
        for (int n = 0; n < 2; ++n) {
          acc[m][n] = __builtin_amdgcn_mfma_f32_16x16x32_bf16(ah[m], bh[n], acc[m][n], 0, 0, 0);
          acc[m][n] = __builtin_amdgcn_mfma_f32_16x16x32_bf16(ah[m], bl[n], acc[m][n], 0, 0, 0);
          acc[m][n] = __builtin_amdgcn_mfma_f32_16x16x32_bf16(al[m], bh[n], acc[m][n], 0, 0, 0);
        }
    }
    __syncthreads();
  }

  #pragma unroll
  for (int m = 0; m < 4; ++m)
    #pragma unroll
    for (int n = 0; n < 2; ++n) {
      const int col = n0 + wn * 32 + n * 16 + lm;
      #pragma unroll
      for (int r = 0; r < 4; ++r) {
        const int row = m0 + wm * 64 + m * 16 + lk * 4 + r;
        Pz[(size_t)row * N + col] = acc[m][n][r];
      }
    }
}

// ---------------------------------------------------------------------------
// Head: h2 = gelu(sum_z P2z + b2) on the fly; z = h2 @ Wh + bh; p = sigmoid.
// Emits logits, T=20*p, E=exp(20*p), L=exp(20*label), MSE into spread slots.
// ---------------------------------------------------------------------------
template<int NZ>
__global__ __launch_bounds__(256) void head_kernel(
    const float* __restrict__ P2, const float* __restrict__ b2,
    const float* __restrict__ Wh, const float* __restrict__ bh,
    const float* __restrict__ labels,
    float* __restrict__ logits_out, float* __restrict__ To,
    float* __restrict__ Eo, float* __restrict__ Lo,
    double* __restrict__ mse_slots) {
  const int lane = threadIdx.x & 63;
  const int wv   = threadIdx.x >> 6;
  const int row  = blockIdx.x * 4 + wv;
  const size_t base = (size_t)row * 256;
  constexpr size_t ZSTRIDE = (size_t)4096 * 256;
  float a0 = 0.f, a1 = 0.f, a2 = 0.f, a3 = 0.f;
  #pragma unroll
  for (int q = 0; q < 4; ++q) {
    const int k = lane + q * 64;
    float s = b2[k];
    #pragma unroll
    for (int z = 0; z < NZ; ++z) s += P2[z * ZSTRIDE + base + k];
    const float hv = gelu_exact(s);
    const float4 wv4 = *(const float4*)&Wh[k * 4];
    a0 = fmaf(hv, wv4.x, a0); a1 = fmaf(hv, wv4.y, a1);
    a2 = fmaf(hv, wv4.z, a2); a3 = fmaf(hv, wv4.w, a3);
  }
  #pragma unroll
  for (int off = 32; off > 0; off >>= 1) {
    a0 += __shfl_down(a0, off, 64);
    a1 += __shfl_down(a1, off, 64);
    a2 += __shfl_down(a2, off, 64);
    a3 += __shfl_down(a3, off, 64);
  }
  if (lane == 0) {
    const float z[4] = {a0 + bh[0], a1 + bh[1], a2 + bh[2], a3 + bh[3]};
    float msew = 0.f;
    #pragma unroll
    for (int d = 0; d < 4; ++d) {
      const float p = 1.0f / (1.0f + expf(-z[d]));
      const float lab = labels[row * 4 + d];
      logits_out[row * 4 + d] = p;
      To[row * 4 + d] = 20.0f * p;
      Eo[row * 4 + d] = expf(20.0f * p);
      Lo[row * 4 + d] = expf(20.0f * lab);
      const float df = p - lab;
      msew = fmaf(df, df, msew);
    }
    atomicAdd(&mse_slots[row & 31], (double)msew);
  }
}

// ---------------------------------------------------------------------------
// Pairwise ordering loss: one WAVE per HALF of a 64x64 upper-triangle tile
// (2080 tiles x 2 halves = 4160 waves, 1040 blocks).  All data in registers;
// j broadcast via readlane (uniform index -> SGPR).  No LDS, no barriers.
//   p = Ei/(Ei+Ej);  bce = log(Ei+Ej) - Tj - t*(Ti-Tj);  t = Li/(Li+Lj)
//   label gate |li-lj|>0.01  <=>  |t - 0.5| > sigmoid(0.2)-0.5
// Slot-spread fire-and-forget atomics (32 slots per quantity).
// ---------------------------------------------------------------------------
#define GFUN(t) ((t) * 64 - (t) * ((t) - 1) / 2)
#define TGATE 0.0498339962f

__global__ __launch_bounds__(256) void pairwise_kernel(
    const float* __restrict__ To, const float* __restrict__ E,
    const float* __restrict__ L, double* __restrict__ slots) {
  const int lane = threadIdx.x & 63;
  const int wv   = threadIdx.x >> 6;
  const int idx  = blockIdx.x * 4 + wv;     // 0..4159
  const int tile = idx >> 1;
  const int jbase = (idx & 1) * 32;

  int ti = (int)((129.0f - sqrtf(fmaxf(16641.0f - 8.0f * (float)tile, 0.f))) * 0.5f);
  if (ti < 0) ti = 0; if (ti > 63) ti = 63;
  while (ti > 0 && GFUN(ti) > tile) ti--;
  while (ti < 63 && GFUN(ti + 1) <= tile) ti++;
  const int tj = ti + (tile - GFUN(ti));
  const int i0 = ti * 64, j0 = tj * 64;
  const int i = i0 + lane, j = j0 + lane;

  const float4 e4 = *(const float4*)&E[(size_t)i * 4];
  const float4 t4 = *(const float4*)&To[(size_t)i * 4];
  const float4 l4 = *(const float4*)&L[(size_t)i * 4];
  const float Ei[4] = {e4.x, e4.y, e4.z, e4.w};
  const float Ti[4] = {t4.x, t4.y, t4.z, t4.w};
  const float Li[4] = {l4.x, l4.y, l4.z, l4.w};
  const float4 ej4 = *(const float4*)&E[(size_t)j * 4];
  const float4 tj4 = *(const float4*)&To[(size_t)j * 4];
  const float4 lj4 = *(const float4*)&L[(size_t)j * 4];
  const float Ejv[4] = {ej4.x, ej4.y, ej4.z, ej4.w};
  const float Tjv[4] = {tj4.x, tj4.y, tj4.z, tj4.w};
  const float Ljv[4] = {lj4.x, lj4.y, lj4.z, lj4.w};

  const bool diag = (ti == tj);
  float acc[4] = {0.f, 0.f, 0.f, 0.f};
  int cnt = 0;
  #pragma unroll 8
  for (int s = 0; s < 32; ++s) {
    const int jj = jbase + s;
    const bool jok = !diag || (jj > lane);
    #pragma unroll
    for (int d = 0; d < 4; ++d) {
      const float Ej = rlane(Ejv[d], jj);
      const float Tj = rlane(Tjv[d], jj);
      const float Lj = rlane(Ljv[d], jj);
      const float logse = __logf(Ei[d] + Ej);
      const float tt = Li[d] * __builtin_amdgcn_rcpf(Li[d] + Lj);
      const float bce = (logse - Tj) - tt * (Ti[d] - Tj);
      const bool m = jok && (fabsf(tt - 0.5f) > TGATE);
      acc[d] += m ? bce : 0.f;
      cnt += m ? 1 : 0;
    }
  }

  float tot = (acc[0] + acc[1]) + (acc[2] + acc[3]);
  #pragma unroll
  for (int off = 32; off > 0; off >>= 1) {
    tot += __shfl_down(tot, off, 64);
    cnt += __shfl_down(cnt, off, 64);
  }
  if (lane == 0) {
    const int sl = idx & 31;
    atomicAdd(&slots[32 + sl], (double)tot);
    atomicAdd((u64*)(slots + 64) + sl, (u64)cnt);
  }
}

// ---------------------------------------------------------------------------
// finalize: reduce the 32-slot accumulators, write the scalar loss.
// ---------------------------------------------------------------------------
__global__ void finalize_kernel(const double* __restrict__ slots,
                                float* __restrict__ out) {
  const int l = threadIdx.x;   // 64 threads
  double m = (l < 32) ? slots[l] : 0.0;
  double o = (l < 32) ? slots[32 + l] : 0.0;
  double c = (l < 32) ? (double)((const u64*)(slots + 64))[l] : 0.0;
  #pragma unroll
  for (int off = 32; off > 0; off >>= 1) {
    m += __shfl_down(m, off, 64);
    o += __shfl_down(o, off, 64);
    c += __shfl_down(c, off, 64);
  }
  if (l == 0) {
    const double mse = m / (4096.0 * 4.0);
    const double ord = (c > 0.0) ? (o / c) : 0.0;
    out[0] = (float)(0.5 * mse + 0.5 * ord);
  }
}

// ---------------------------------------------------------------------------
extern "C" void kernel_launch(void* const* d_in, const int* in_sizes, int n_in,
                              void* d_out, int out_size, void* d_ws, size_t ws_size,
                              hipStream_t stream) {
  const float* pooled = (const float*)d_in[0];
  const float* labels = (const float*)d_in[1];
  const float* ln1_g  = (const float*)d_in[2];
  const float* ln1_b  = (const float*)d_in[3];
  const float* W1     = (const float*)d_in[4];
  const float* b1     = (const float*)d_in[5];
  const float* ln2_g  = (const float*)d_in[6];
  const float* ln2_b  = (const float*)d_in[7];
  const float* W2     = (const float*)d_in[8];
  const float* b2     = (const float*)d_in[9];
  const float* Wh     = (const float*)d_in[10];
  const float* bh     = (const float*)d_in[11];
  float* out = (float*)d_out;

  // ws layout (bytes), peak 35651584 (34.0 MiB):
  //  phase1: xhi 8M@0 | xlo 8M@8M | w1thi 1M@16777216 | w1tlo 1M@17825792 |
  //          P1 2x8M@18874368..35651584
  //  phase2 (xhi/xlo/w1t dead): h1nhi 4M@0 | h1nlo 4M@4194304 |
  //          w2thi 256K@8388608 | w2tlo 256K@8650752 |
  //          P2 4x4M@8912896..25690112 (overlaps dead P1 head only)
  //  loss scratch in dead-P1 beyond P2 (zeroed by gemm2, after P1's last
  //          reader): E/T/L 64K each @25690112.. | slots @25886720
  //          (slots: mse d[32] | ord d[32] | cnt u64[32] = 768 B)
  char* ws = (char*)d_ws;
  u16*   xhi   = (u16*)(ws + 0);
  u16*   xlo   = (u16*)(ws + 8388608);
  u16*   w1thi = (u16*)(ws + 16777216);
  u16*   w1tlo = (u16*)(ws + 17825792);
  float* P1    = (float*)(ws + 18874368);
  u16*   h1nhi = (u16*)(ws + 0);
  u16*   h1nlo = (u16*)(ws + 4194304);
  u16*   w2thi = (u16*)(ws + 8388608);
  u16*   w2tlo = (u16*)(ws + 8650752);
  float* P2    = (float*)(ws + 8912896);
  float* Eo    = (float*)(ws + 25690112);
  float* To    = (float*)(ws + 25755648);
  float* Lo    = (float*)(ws + 25821184);
  double* slots = (double*)(ws + 25886720);

  prep_kernel<<<4256, 256, 0, stream>>>(pooled, ln1_g, ln1_b, W1, W2,
                                        xhi, xlo, w1thi, w1tlo, w2thi, w2tlo);
  gemm_bf16x3_partial<4096, 512, 1024, 512><<<dim3(8, 32, 2), 256, 0, stream>>>(
      xhi, xlo, w1thi, w1tlo, P1, nullptr);
  ln_gelu_split_kernel<512, 2><<<4096, 256, 0, stream>>>(
      P1, P1 + (size_t)4096 * 512, b1, ln2_g, ln2_b, h1nhi, h1nlo);
  gemm_bf16x3_partial<4096, 256, 512, 128><<<dim3(4, 32, 4), 256, 0, stream>>>(
      h1nhi, h1nlo, w2thi, w2tlo, P2, slots);
  head_kernel<4><<<1024, 256, 0, stream>>>(
      P2, b2, Wh, bh, labels, out + 1, To, Eo, Lo, slots);
  pairwise_kernel<<<1040, 256, 0, stream>>>(To, Eo, Lo, slots);
  finalize_kernel<<<1, 64, 0, stream>>>(slots, out);
}